// Round 2
// baseline (127.684 us; speedup 1.0000x reference)
//
#include <hip/hip_runtime.h>
#include <hip/hip_bf16.h>
#include <stdint.h>

typedef __attribute__((ext_vector_type(4))) float f32x4;
typedef __attribute__((ext_vector_type(8))) short s16x8;

#define KSCALE 0.1803368801111204f  /* 1/(8*ln2): exp2(q*k*KSCALE) = exp(q*k/8) */

__device__ __forceinline__ short f2bf(float x) {
  __bf16 h = (__bf16)x;
  return __builtin_bit_cast(short, h);
}

// ---- prep: convert weights to bf16 in workspace, fold softmax scale into Wk/bk ----
__global__ void prep_kernel(const float* __restrict__ Wq, const float* __restrict__ Wk,
                            const float* __restrict__ Wv, const float* __restrict__ bq,
                            const float* __restrict__ bk, const float* __restrict__ bv,
                            const float* __restrict__ Wo,
                            short* __restrict__ wqkv, short* __restrict__ wo,
                            float* __restrict__ bias) {
  int idx = blockIdx.x * 256 + threadIdx.x;
  if (idx < 192 * 256) {
    int r = idx >> 8, c = idx & 255;
    float v;
    if (r < 64)       v = Wq[r * 256 + c];
    else if (r < 128) v = Wk[(r - 64) * 256 + c] * KSCALE;
    else              v = Wv[(r - 128) * 256 + c];
    wqkv[idx] = f2bf(v);
  } else if (idx < 192 * 256 + 256 * 64) {
    int i2 = idx - 192 * 256;
    wo[i2] = f2bf(Wo[i2]);
  } else if (idx < 192 * 256 + 256 * 64 + 192) {
    int r = idx - (192 * 256 + 256 * 64);
    float v = (r < 64) ? bq[r] : (r < 128) ? bk[r - 64] * KSCALE : bv[r - 128];
    bias[r] = v;
  }
}

// LDS map (28672 B):  [0,16384) x-tile bf16 [32][256]  (phase 1 only)
//   reused after barrier: [0,8192) q f32 [32][64] ; [8192,16384) k' f32 [32][64]
//   [16384,24576) v f32 [32][64] ; [24576,28672) AO bf16 [32][64]
// All rows XOR-swizzled: byte ^= (row&7)<<4  (kills D-stride bank conflicts, G4)
__global__ __launch_bounds__(256, 4)
void fused_attn(const float* __restrict__ x,
                const short* __restrict__ wqkv,
                const short* __restrict__ wo,
                const float* __restrict__ biasqkv,
                const float* __restrict__ bo,
                float* __restrict__ out) {
  __shared__ __align__(16) char smem[28672];
  const int tid = threadIdx.x;
  const int lane = tid & 63;
  const int w = tid >> 6;
  const int l15 = lane & 15;
  const int g = lane >> 4;
  const int rowbase = blockIdx.x * 32;

  // ---- stage x tile: f32 -> bf16, swizzled ----
#pragma unroll
  for (int it = 0; it < 8; ++it) {
    int flat4 = it * 256 + tid;
    int r = flat4 >> 6;
    int c4 = flat4 & 63;
    const f32x4 xv = *reinterpret_cast<const f32x4*>(x + (size_t)(rowbase + r) * 256 + c4 * 4);
    unsigned p0 = (unsigned short)f2bf(xv[0]) | ((unsigned)(unsigned short)f2bf(xv[1]) << 16);
    unsigned p1 = (unsigned short)f2bf(xv[2]) | ((unsigned)(unsigned short)f2bf(xv[3]) << 16);
    int byte = (r * 512 + c4 * 8) ^ ((r & 7) << 4);
    uint2* p = reinterpret_cast<uint2*>(smem + byte);
    p->x = p0; p->y = p1;
  }
  __syncthreads();

  // ---- phase 1: C[32][192] = X @ Wqkv^T  (wave w owns coltiles 3w..3w+2) ----
  f32x4 acc1[2][3];
#pragma unroll
  for (int rt = 0; rt < 2; ++rt)
#pragma unroll
    for (int ct = 0; ct < 3; ++ct) acc1[rt][ct] = (f32x4){0.f, 0.f, 0.f, 0.f};

  const int ct0 = w * 3;
#pragma unroll
  for (int ks = 0; ks < 8; ++ks) {
    s16x8 afr[2];
#pragma unroll
    for (int rt = 0; rt < 2; ++rt) {
      int r = rt * 16 + l15;
      int byte = (r * 512 + ks * 64 + g * 16) ^ ((r & 7) << 4);
      afr[rt] = *reinterpret_cast<const s16x8*>(smem + byte);
    }
#pragma unroll
    for (int ct = 0; ct < 3; ++ct) {
      int n = (ct0 + ct) * 16 + l15;
      s16x8 bfr = *reinterpret_cast<const s16x8*>(wqkv + (size_t)n * 256 + ks * 32 + g * 8);
#pragma unroll
      for (int rt = 0; rt < 2; ++rt)
        acc1[rt][ct] = __builtin_amdgcn_mfma_f32_16x16x32_bf16(afr[rt], bfr, acc1[rt][ct], 0, 0, 0);
    }
  }
  __syncthreads();  // all x-tile reads done; LDS reused for q/k'

  // epilogue: + bias, scatter to q / k' / v LDS (C/D layout: col=l&15, row=(l>>4)*4+reg)
#pragma unroll
  for (int ct = 0; ct < 3; ++ct) {
    int cg = (ct0 + ct) * 16 + l15;  // 0..191
    float bb = biasqkv[cg];
    int arr = cg >> 6;               // 0=q 1=k' 2=v
    int cc = cg & 63;
    int base = arr * 8192;
#pragma unroll
    for (int rt = 0; rt < 2; ++rt)
#pragma unroll
      for (int rg = 0; rg < 4; ++rg) {
        int r = rt * 16 + g * 4 + rg;
        int byte = (base + r * 256 + cc * 4) ^ ((r & 7) << 4);
        *reinterpret_cast<float*>(smem + byte) = acc1[rt][ct][rg] + bb;
      }
  }
  __syncthreads();

  // ---- phase 2: per-sample softmax attention (wave w owns samples 8w..8w+7) ----
  // D[c][i] = sum_j Vm^T[c][j] * E[i][j], Vm^T row0=v, row1=1 -> c=0 num, c=1 den
#pragma unroll 1
  for (int si = 0; si < 8; ++si) {
    int s = w * 8 + si;
    int swz = (s & 7) << 4;
    f32x4 kf[2][2];
#pragma unroll
    for (int jh = 0; jh < 2; ++jh) {
      int raw = 8192 + s * 256 + jh * 128 + g * 32;
      kf[jh][0] = *reinterpret_cast<const f32x4*>(smem + (raw ^ swz));
      kf[jh][1] = *reinterpret_cast<const f32x4*>(smem + ((raw + 16) ^ swz));
    }
    s16x8 vfr[2];
#pragma unroll
    for (int jh = 0; jh < 2; ++jh) {
      s16x8 t = (s16x8){0, 0, 0, 0, 0, 0, 0, 0};
      if (l15 == 0) {
        int raw = 16384 + s * 256 + jh * 128 + g * 32;
        f32x4 v0 = *reinterpret_cast<const f32x4*>(smem + (raw ^ swz));
        f32x4 v1 = *reinterpret_cast<const f32x4*>(smem + ((raw + 16) ^ swz));
        t[0] = f2bf(v0[0]); t[1] = f2bf(v0[1]); t[2] = f2bf(v0[2]); t[3] = f2bf(v0[3]);
        t[4] = f2bf(v1[0]); t[5] = f2bf(v1[1]); t[6] = f2bf(v1[2]); t[7] = f2bf(v1[3]);
      } else if (l15 == 1) {
        short one = f2bf(1.0f);
        t = (s16x8){one, one, one, one, one, one, one, one};
      }
      vfr[jh] = t;
    }
#pragma unroll
    for (int it = 0; it < 4; ++it) {
      int rawq = s * 256 + (it * 16 + l15) * 4;
      float qi = *reinterpret_cast<const float*>(smem + (rawq ^ swz));
      f32x4 acc = (f32x4){0.f, 0.f, 0.f, 0.f};
#pragma unroll
      for (int jh = 0; jh < 2; ++jh) {
        s16x8 ef;
#pragma unroll
        for (int h = 0; h < 2; ++h)
#pragma unroll
          for (int e4 = 0; e4 < 4; ++e4)
            ef[h * 4 + e4] = f2bf(__builtin_amdgcn_exp2f(qi * kf[jh][h][e4]));
        acc = __builtin_amdgcn_mfma_f32_16x16x32_bf16(vfr[jh], ef, acc, 0, 0, 0);
      }
      if (lane < 16) {  // g==0: reg0 = num (c=0), reg1 = den (c=1), col = i
        float o = acc[0] * __builtin_amdgcn_rcpf(acc[1]);
        int raw = 24576 + s * 128 + (it * 16 + lane) * 2;
        *reinterpret_cast<short*>(smem + (raw ^ swz)) = f2bf(o);
      }
    }
  }
  __syncthreads();

  // ---- phase 3: Y[32][256] = AO @ Wo^T + bo  (wave w owns coltiles 4w..4w+3) ----
  f32x4 acc3[2][4];
#pragma unroll
  for (int rt = 0; rt < 2; ++rt)
#pragma unroll
    for (int ct = 0; ct < 4; ++ct) acc3[rt][ct] = (f32x4){0.f, 0.f, 0.f, 0.f};
  const int ct3 = w * 4;
#pragma unroll
  for (int ks = 0; ks < 2; ++ks) {
    s16x8 afr[2];
#pragma unroll
    for (int rt = 0; rt < 2; ++rt) {
      int r = rt * 16 + l15;
      int byte = (24576 + r * 128 + ks * 64 + g * 16) ^ ((r & 7) << 4);
      afr[rt] = *reinterpret_cast<const s16x8*>(smem + byte);
    }
#pragma unroll
    for (int ct = 0; ct < 4; ++ct) {
      int n = (ct3 + ct) * 16 + l15;
      s16x8 bfr = *reinterpret_cast<const s16x8*>(wo + (size_t)n * 64 + ks * 32 + g * 8);
#pragma unroll
      for (int rt = 0; rt < 2; ++rt)
        acc3[rt][ct] = __builtin_amdgcn_mfma_f32_16x16x32_bf16(afr[rt], bfr, acc3[rt][ct], 0, 0, 0);
    }
  }
#pragma unroll
  for (int ct = 0; ct < 4; ++ct) {
    int n = (ct3 + ct) * 16 + l15;
    float bov = bo[n];
#pragma unroll
    for (int rt = 0; rt < 2; ++rt)
#pragma unroll
      for (int rg = 0; rg < 4; ++rg) {
        int r = rowbase + rt * 16 + g * 4 + rg;
        out[(size_t)r * 256 + n] = acc3[rt][ct][rg] + bov;
      }
  }
}

extern "C" void kernel_launch(void* const* d_in, const int* in_sizes, int n_in,
                              void* d_out, int out_size, void* d_ws, size_t ws_size,
                              hipStream_t stream) {
  const float* x  = (const float*)d_in[0];
  const float* Wq = (const float*)d_in[1];
  const float* bq = (const float*)d_in[2];
  const float* Wk = (const float*)d_in[3];
  const float* bk = (const float*)d_in[4];
  const float* Wv = (const float*)d_in[5];
  const float* bv = (const float*)d_in[6];
  const float* Wo = (const float*)d_in[7];
  const float* bo = (const float*)d_in[8];
  float* out = (float*)d_out;

  short* wqkv = (short*)d_ws;              // [192][256] bf16
  short* wo   = wqkv + 192 * 256;          // [256][64] bf16
  float* bias = (float*)((char*)d_ws + 131072);  // [192] f32

  prep_kernel<<<257, 256, 0, stream>>>(Wq, Wk, Wv, bq, bk, bv, Wo, wqkv, wo, bias);
  fused_attn<<<1024, 256, 0, stream>>>(x, wqkv, wo, bias, bo, out);
}